// Round 3
// baseline (660.305 us; speedup 1.0000x reference)
//
#include <hip/hip_runtime.h>
#include <math.h>

#define B_ 16
#define T_ 2048
#define H_ 512
#define K_ 15
#define M_ (B_*T_)   // 32768

typedef __attribute__((ext_vector_type(8))) short short8;
typedef __attribute__((ext_vector_type(4))) float f32x4;

__device__ __forceinline__ unsigned short f2bf(float f) {
  union { float f; unsigned u; } v; v.f = f;
  unsigned r = v.u + 0x7FFFu + ((v.u >> 16) & 1u);
  return (unsigned short)(r >> 16);
}
__device__ __forceinline__ float bf2f(unsigned short b) {
  union { float f; unsigned u; } v; v.u = ((unsigned)b) << 16;
  return v.f;
}

__device__ __forceinline__ void async_load16(const void* g, void* l) {
  __builtin_amdgcn_global_load_lds((const __attribute__((address_space(1))) void*)g,
                                   (__attribute__((address_space(3))) void*)l, 16, 0, 0);
}

// ---------------- fp32 -> (bf16 hi, bf16 lo) split conversion ----------------
__global__ void convx_k(const float* __restrict__ x, unsigned short* __restrict__ hi,
                        unsigned short* __restrict__ lo, int n4) {
  int i = blockIdx.x * blockDim.x + threadIdx.x;
  int stride = gridDim.x * blockDim.x;
  for (; i < n4; i += stride) {
    float4 v = ((const float4*)x)[i];
    ushort4 h, l;
    h.x = f2bf(v.x); l.x = f2bf(v.x - bf2f(h.x));
    h.y = f2bf(v.y); l.y = f2bf(v.y - bf2f(h.y));
    h.z = f2bf(v.z); l.z = f2bf(v.z - bf2f(h.z));
    h.w = f2bf(v.w); l.w = f2bf(v.w - bf2f(h.w));
    ((ushort4*)hi)[i] = h;
    ((ushort4*)lo)[i] = l;
  }
}

// ---------------- w_eff[h] = sum_o pw2_w[o,h]*lin_w[o] ----------------------
__global__ __launch_bounds__(256) void weff_k(const float* __restrict__ pw2_w,
    const float* __restrict__ lin_w, float* __restrict__ weff) {
  __shared__ float red[256];
  int h = blockIdx.x * 64 + (threadIdx.x & 63);
  int og = threadIdx.x >> 6;
  float acc = 0.f;
  for (int o = og * 128; o < og * 128 + 128; ++o) acc += pw2_w[o * H_ + h] * lin_w[o];
  red[threadIdx.x] = acc;
  __syncthreads();
  if (threadIdx.x < 64)
    weff[h] = red[threadIdx.x] + red[threadIdx.x + 64] + red[threadIdx.x + 128] + red[threadIdx.x + 192];
}

__global__ void beff_k(const float* __restrict__ pw2_b, const float* __restrict__ lin_w,
                       const float* __restrict__ lin_b, float* __restrict__ weff) {
  __shared__ float red[512];
  int h = threadIdx.x;
  red[h] = pw2_b[h] * lin_w[h];
  __syncthreads();
  for (int s = 256; s > 0; s >>= 1) {
    if (h < s) red[h] += red[h + s];
    __syncthreads();
  }
  if (h == 0) weff[H_] = red[0] + lin_b[0];
}

// ---------------- pw1 GEMM via bf16 hi/lo-split MFMA + GLU epilogue ----------
__global__ __launch_bounds__(256) void gemm_mfma_k(
    const unsigned short* __restrict__ Ahi, const unsigned short* __restrict__ Alo,
    const unsigned short* __restrict__ Whi, const unsigned short* __restrict__ Wlo,
    const float* __restrict__ bias, float* __restrict__ g) {
  __shared__ short As[128 * 64];
  __shared__ short Bs[128 * 64];
  const int tid = threadIdx.x;
  const int m0 = blockIdx.x * 128;
  const int n0 = blockIdx.y * 64;
  const int w = tid >> 6;
  const int lane = tid & 63;

  f32x4 acc[2][8];
#pragma unroll
  for (int mt = 0; mt < 2; ++mt)
#pragma unroll
    for (int nt = 0; nt < 8; ++nt) acc[mt][nt] = (f32x4){0.f, 0.f, 0.f, 0.f};

  const unsigned short* Aptr[3] = {Ahi, Alo, Ahi};
  const unsigned short* Bptr[3] = {Whi, Whi, Wlo};

  const int srow[4] = {(0 * 256 + tid) >> 3, (1 * 256 + tid) >> 3,
                       (2 * 256 + tid) >> 3, (3 * 256 + tid) >> 3};
  const int scc = tid & 7;

  for (int p = 0; p < 3; ++p) {
    const unsigned short* Ab = Aptr[p];
    const unsigned short* Bb = Bptr[p];
#pragma unroll 1
    for (int kk = 0; kk < 8; ++kk) {
      const int k0 = kk * 64;
      __syncthreads();
#pragma unroll
      for (int j = 0; j < 4; ++j) {
        int row = srow[j];
        int csrc = scc ^ (row & 7);
        int lbase = __builtin_amdgcn_readfirstlane((j * 256 + w * 64) * 8);
        async_load16(Ab + (size_t)(m0 + row) * 512 + k0 + csrc * 8, &As[lbase]);
        int wrow = (row < 64) ? (n0 + row) : (n0 + 448 + row);
        async_load16(Bb + (size_t)wrow * 512 + k0 + csrc * 8, &Bs[lbase]);
      }
      __syncthreads();
#pragma unroll
      for (int ks = 0; ks < 2; ++ks) {
        const int swz = (ks * 4 + (lane >> 4)) ^ (lane & 7);
        const int rA = w * 32 + (lane & 15);
        const int rB = lane & 15;
        short8 af[2], bfr[8];
#pragma unroll
        for (int mt = 0; mt < 2; ++mt)
          af[mt] = *(const short8*)&As[((rA + mt * 16) * 8 + swz) * 8];
#pragma unroll
        for (int nt = 0; nt < 8; ++nt)
          bfr[nt] = *(const short8*)&Bs[((rB + nt * 16) * 8 + swz) * 8];
#pragma unroll
        for (int mt = 0; mt < 2; ++mt)
#pragma unroll
          for (int nt = 0; nt < 8; ++nt)
            acc[mt][nt] = __builtin_amdgcn_mfma_f32_16x16x32_bf16(af[mt], bfr[nt], acc[mt][nt], 0, 0, 0);
      }
    }
  }

  const int col = lane & 15, rq = lane >> 4;
#pragma unroll
  for (int mt = 0; mt < 2; ++mt) {
#pragma unroll
    for (int nt = 0; nt < 4; ++nt) {
      int gcol = n0 + nt * 16 + col;
      float ba = bias[gcol];
      float bg = bias[512 + gcol];
#pragma unroll
      for (int r = 0; r < 4; ++r) {
        int grow = m0 + w * 32 + mt * 16 + rq * 4 + r;
        float a = acc[mt][nt][r] + ba;
        float gt = acc[mt][nt + 4][r] + bg;
        g[(size_t)grow * 512 + gcol] = a / (1.f + expf(-gt));
      }
    }
  }
}

// ---------------- depthwise conv + LN + swish + logit-dot + sigmoid ----------
// Writes alphas TRANSPOSED: aT[t*16 + b]
__global__ __launch_bounds__(512) void conv_ln_k(const float* __restrict__ g,
    const float* __restrict__ dw_w, const float* __restrict__ dw_b,
    const float* __restrict__ ln_g, const float* __restrict__ ln_b,
    const float* __restrict__ weff, const int* __restrict__ x_lens,
    float* __restrict__ aT) {
  __shared__ float wlds[H_ * K_];
  __shared__ float red1[16][8];
  __shared__ float red2[16][8];
  __shared__ float mvs[16], rss[16];
  const int tid = threadIdx.x;
  const int c = tid;
  const int t0 = blockIdx.x * 16;
  const int b = blockIdx.y;

  for (int i = tid; i < H_ * K_; i += 512) wlds[i] = dw_w[i];
  __syncthreads();

  const float* gb = g + ((size_t)b * T_) * H_ + c;
  float gv[30];
#pragma unroll
  for (int i = 0; i < 30; ++i) {
    int t = t0 - 14 + i;
    gv[i] = (t >= 0) ? gb[(size_t)t * H_] : 0.f;
  }
  float wreg[15];
#pragma unroll
  for (int k = 0; k < 15; ++k) wreg[k] = wlds[c * 15 + k];
  float dwb = dw_b[c];
  float h2[16];
#pragma unroll
  for (int j = 0; j < 16; ++j) {
    float s = dwb;
#pragma unroll
    for (int k = 0; k < 15; ++k) s += gv[j + k] * wreg[k];
    h2[j] = s;
  }
  const int lane = tid & 63, wid = tid >> 6;
#pragma unroll
  for (int j = 0; j < 16; ++j) {
    float s1 = h2[j], s2 = h2[j] * h2[j];
#pragma unroll
    for (int off = 32; off > 0; off >>= 1) {
      s1 += __shfl_down(s1, off, 64);
      s2 += __shfl_down(s2, off, 64);
    }
    if (lane == 0) { red1[j][wid] = s1; red2[j][wid] = s2; }
  }
  __syncthreads();
  if (tid < 16) {
    float s1 = 0.f, s2 = 0.f;
#pragma unroll
    for (int w = 0; w < 8; ++w) { s1 += red1[tid][w]; s2 += red2[tid][w]; }
    float m = s1 * (1.f / 512.f);
    float v = s2 * (1.f / 512.f) - m * m;
    mvs[tid] = m;
    rss[tid] = rsqrtf(v + 1e-5f);
  }
  __syncthreads();
  float lg = ln_g[c], lb = ln_b[c], we = weff[c];
#pragma unroll
  for (int j = 0; j < 16; ++j) {
    float y = (h2[j] - mvs[j]) * rss[j] * lg + lb;
    float sw = y / (1.f + expf(-y));
    float p = sw * we;
#pragma unroll
    for (int off = 32; off > 0; off >>= 1) p += __shfl_down(p, off, 64);
    if (lane == 0) red1[j][wid] = p;
  }
  __syncthreads();
  if (tid < 16) {
    float s = 0.f;
#pragma unroll
    for (int w = 0; w < 8; ++w) s += red1[tid][w];
    float logit = s + weff[H_];
    float a = 1.f / (1.f + expf(-logit));
    int t = t0 + tid;
    if (t >= x_lens[b]) a = 0.f;
    aT[t * B_ + b] = a;
  }
}

// ---------------- CIF sequential scan (bit-exact reference op order) ---------
// Transposed layouts [t][b]; 8-deep register prefetch; integ' = ni - floor(ni)
// (exact for ni in [0,2): floor is 0 or 1, subtract exact).
__global__ __launch_bounds__(64) void cif_scan_k(const float* __restrict__ aT,
    float* __restrict__ wdT, float* __restrict__ wrT, int* __restrict__ fire_pos,
    int* __restrict__ nfires, float* __restrict__ tok) {
  const int b = threadIdx.x;
  if (b >= B_) return;
  const float* ar = aT + b;
  float* wdr = wdT + b;
  float* wrr = wrT + b;
  int* fp = fire_pos + b * T_;
  float integ = 0.f, tsum = 0.f;
  int cnt = 0;
  float buf[8], nbuf[8];
#pragma unroll
  for (int j = 0; j < 8; ++j) buf[j] = ar[j * B_];
  for (int tb = 0; tb < T_; tb += 8) {
    if (tb + 8 < T_) {
#pragma unroll
      for (int j = 0; j < 8; ++j) nbuf[j] = ar[(tb + 8 + j) * B_];
    }
#pragma unroll
    for (int j = 0; j < 8; ++j) {
      float al = buf[j];
      float dist = 1.0f - integ;
      float ni = integ + al;
      bool fire = ni >= 1.0f;
      float cur = fire ? dist : al;
      wdr[(tb + j) * B_] = cur;
      wrr[(tb + j) * B_] = al - cur;
      if (fire) fp[cnt++] = tb + j;
      integ = ni - floorf(ni);
      tsum += al;
    }
#pragma unroll
    for (int j = 0; j < 8; ++j) buf[j] = nbuf[j];
  }
  nfires[b] = cnt;
  tok[b] = tsum;
}

// ---------------- gather fired frames + reversed copy + zero-fill tail -------
__global__ __launch_bounds__(128) void frames_k(const float* __restrict__ x,
    const float* __restrict__ aT, const float* __restrict__ wdT,
    const float* __restrict__ wrT, const int* __restrict__ fire_pos,
    const int* __restrict__ nfires, float* __restrict__ out0, float* __restrict__ out2) {
  const int b = blockIdx.y;
  const int j = blockIdx.x;
  const int h = threadIdx.x << 2;
  const size_t ob = ((size_t)b * T_ + j) * H_;
  if (j >= nfires[b]) {   // d_out is poisoned 0xAA: zero the unused rows here
    float4 z = make_float4(0.f, 0.f, 0.f, 0.f);
    *(float4*)(out0 + ob + h) = z;
    *(float4*)(out2 + ob + h) = z;
    return;
  }
  const int te = fire_pos[b * T_ + j];
  const int ts = (j > 0) ? fire_pos[b * T_ + j - 1] : -1;
  const float* xb = x + ((size_t)b * T_) * H_;
  float4 acc = make_float4(0.f, 0.f, 0.f, 0.f);
  if (j > 0) {
    float w = wrT[ts * B_ + b];
    float4 xv = *(const float4*)(xb + (size_t)ts * H_ + h);
    acc.x = w * xv.x; acc.y = w * xv.y; acc.z = w * xv.z; acc.w = w * xv.w;
  }
  for (int t = ts + 1; t < te; ++t) {
    float w = aT[t * B_ + b];
    float4 xv = *(const float4*)(xb + (size_t)t * H_ + h);
    acc.x += w * xv.x; acc.y += w * xv.y; acc.z += w * xv.z; acc.w += w * xv.w;
  }
  {
    float w = wdT[te * B_ + b];
    float4 xv = *(const float4*)(xb + (size_t)te * H_ + h);
    acc.x += w * xv.x; acc.y += w * xv.y; acc.z += w * xv.z; acc.w += w * xv.w;
  }
  *(float4*)(out0 + ob + h) = acc;
  float4 racc = make_float4(acc.w, acc.z, acc.y, acc.x);
  *(float4*)(out2 + ob + (H_ - 4 - h)) = racc;
}

extern "C" void kernel_launch(void* const* d_in, const int* in_sizes, int n_in,
                              void* d_out, int out_size, void* d_ws, size_t ws_size,
                              hipStream_t stream) {
  const float* x     = (const float*)d_in[0];
  const int*   xlens = (const int*)d_in[1];
  const float* pw1_w = (const float*)d_in[2];
  const float* pw1_b = (const float*)d_in[3];
  const float* dw_w  = (const float*)d_in[4];
  const float* dw_b  = (const float*)d_in[5];
  const float* ln_g  = (const float*)d_in[6];
  const float* ln_b  = (const float*)d_in[7];
  const float* pw2_w = (const float*)d_in[8];
  const float* pw2_b = (const float*)d_in[9];
  const float* lin_w = (const float*)d_in[10];
  const float* lin_b = (const float*)d_in[11];

  float* out0 = (float*)d_out;                       // fired_frames (B,T,H)
  float* tok  = out0 + (size_t)B_ * T_ * H_;         // predicted_token_nums (B,)
  float* out2 = tok + B_;                            // r_fired_frames (B,T,H)

  char* ws = (char*)d_ws;
  float* g             = (float*)ws;                              // 64 MB
  unsigned short* Ahi  = (unsigned short*)(ws + (size_t)M_ * H_ * 4);
  unsigned short* Alo  = Ahi + (size_t)M_ * H_;
  unsigned short* Whi  = Alo + (size_t)M_ * H_;
  unsigned short* Wlo  = Whi + (size_t)2 * H_ * H_;
  float* aT       = (float*)(Wlo + (size_t)2 * H_ * H_);
  float* wdT      = aT + B_ * T_;
  float* wrT      = wdT + B_ * T_;
  int*   fire_pos = (int*)(wrT + B_ * T_);
  int*   nfires   = fire_pos + B_ * T_;
  float* weff     = (float*)(nfires + 64);

  convx_k<<<2048, 256, 0, stream>>>(x, Ahi, Alo, M_ * H_ / 4);
  convx_k<<<256, 256, 0, stream>>>(pw1_w, Whi, Wlo, 2 * H_ * H_ / 4);
  weff_k<<<8, 256, 0, stream>>>(pw2_w, lin_w, weff);
  beff_k<<<1, 512, 0, stream>>>(pw2_b, lin_w, lin_b, weff);
  gemm_mfma_k<<<dim3(256, 8), 256, 0, stream>>>(Ahi, Alo, Whi, Wlo, pw1_b, g);
  conv_ln_k<<<dim3(128, 16), 512, 0, stream>>>(g, dw_w, dw_b, ln_g, ln_b, weff, xlens, aT);
  cif_scan_k<<<1, 64, 0, stream>>>(aT, wdT, wrT, fire_pos, nfires, tok);
  frames_k<<<dim3(2048, 16), 128, 0, stream>>>(x, aT, wdT, wrT, fire_pos, nfires, out0, out2);
}

// Round 4
// 497.679 us; speedup vs baseline: 1.3268x; 1.3268x over previous
//
#include <hip/hip_runtime.h>
#include <math.h>

#define B_ 16
#define T_ 2048
#define H_ 512
#define K_ 15
#define M_ (B_*T_)   // 32768

typedef __attribute__((ext_vector_type(8))) short short8;
typedef __attribute__((ext_vector_type(4))) float f32x4;

__device__ __forceinline__ unsigned short f2bf(float f) {
  union { float f; unsigned u; } v; v.f = f;
  unsigned r = v.u + 0x7FFFu + ((v.u >> 16) & 1u);
  return (unsigned short)(r >> 16);
}
__device__ __forceinline__ float bf2f(unsigned short b) {
  union { float f; unsigned u; } v; v.u = ((unsigned)b) << 16;
  return v.f;
}

__device__ __forceinline__ void async_load16(const void* g, void* l) {
  __builtin_amdgcn_global_load_lds((const __attribute__((address_space(1))) void*)g,
                                   (__attribute__((address_space(3))) void*)l, 16, 0, 0);
}

// ---------------- fp32 -> (bf16 hi, bf16 lo) split conversion ----------------
__global__ void convx_k(const float* __restrict__ x, unsigned short* __restrict__ hi,
                        unsigned short* __restrict__ lo, int n4) {
  int i = blockIdx.x * blockDim.x + threadIdx.x;
  int stride = gridDim.x * blockDim.x;
  for (; i < n4; i += stride) {
    float4 v = ((const float4*)x)[i];
    ushort4 h, l;
    h.x = f2bf(v.x); l.x = f2bf(v.x - bf2f(h.x));
    h.y = f2bf(v.y); l.y = f2bf(v.y - bf2f(h.y));
    h.z = f2bf(v.z); l.z = f2bf(v.z - bf2f(h.z));
    h.w = f2bf(v.w); l.w = f2bf(v.w - bf2f(h.w));
    ((ushort4*)hi)[i] = h;
    ((ushort4*)lo)[i] = l;
  }
}

// ---------------- w_eff[h] = sum_o pw2_w[o,h]*lin_w[o] ----------------------
__global__ __launch_bounds__(256) void weff_k(const float* __restrict__ pw2_w,
    const float* __restrict__ lin_w, float* __restrict__ weff) {
  __shared__ float red[256];
  int h = blockIdx.x * 64 + (threadIdx.x & 63);
  int og = threadIdx.x >> 6;
  float acc = 0.f;
  for (int o = og * 128; o < og * 128 + 128; ++o) acc += pw2_w[o * H_ + h] * lin_w[o];
  red[threadIdx.x] = acc;
  __syncthreads();
  if (threadIdx.x < 64)
    weff[h] = red[threadIdx.x] + red[threadIdx.x + 64] + red[threadIdx.x + 128] + red[threadIdx.x + 192];
}

__global__ void beff_k(const float* __restrict__ pw2_b, const float* __restrict__ lin_w,
                       const float* __restrict__ lin_b, float* __restrict__ weff) {
  __shared__ float red[512];
  int h = threadIdx.x;
  red[h] = pw2_b[h] * lin_w[h];
  __syncthreads();
  for (int s = 256; s > 0; s >>= 1) {
    if (h < s) red[h] += red[h + s];
    __syncthreads();
  }
  if (h == 0) weff[H_] = red[0] + lin_b[0];
}

// ---------------- pw1 GEMM via bf16 hi/lo-split MFMA + GLU epilogue ----------
__global__ __launch_bounds__(256) void gemm_mfma_k(
    const unsigned short* __restrict__ Ahi, const unsigned short* __restrict__ Alo,
    const unsigned short* __restrict__ Whi, const unsigned short* __restrict__ Wlo,
    const float* __restrict__ bias, float* __restrict__ g) {
  __shared__ short As[128 * 64];
  __shared__ short Bs[128 * 64];
  const int tid = threadIdx.x;
  const int m0 = blockIdx.x * 128;
  const int n0 = blockIdx.y * 64;
  const int w = tid >> 6;
  const int lane = tid & 63;

  f32x4 acc[2][8];
#pragma unroll
  for (int mt = 0; mt < 2; ++mt)
#pragma unroll
    for (int nt = 0; nt < 8; ++nt) acc[mt][nt] = (f32x4){0.f, 0.f, 0.f, 0.f};

  const unsigned short* Aptr[3] = {Ahi, Alo, Ahi};
  const unsigned short* Bptr[3] = {Whi, Whi, Wlo};

  const int srow[4] = {(0 * 256 + tid) >> 3, (1 * 256 + tid) >> 3,
                       (2 * 256 + tid) >> 3, (3 * 256 + tid) >> 3};
  const int scc = tid & 7;

  for (int p = 0; p < 3; ++p) {
    const unsigned short* Ab = Aptr[p];
    const unsigned short* Bb = Bptr[p];
#pragma unroll 1
    for (int kk = 0; kk < 8; ++kk) {
      const int k0 = kk * 64;
      __syncthreads();
#pragma unroll
      for (int j = 0; j < 4; ++j) {
        int row = srow[j];
        int csrc = scc ^ (row & 7);
        int lbase = __builtin_amdgcn_readfirstlane((j * 256 + w * 64) * 8);
        async_load16(Ab + (size_t)(m0 + row) * 512 + k0 + csrc * 8, &As[lbase]);
        int wrow = (row < 64) ? (n0 + row) : (n0 + 448 + row);
        async_load16(Bb + (size_t)wrow * 512 + k0 + csrc * 8, &Bs[lbase]);
      }
      __syncthreads();
#pragma unroll
      for (int ks = 0; ks < 2; ++ks) {
        const int swz = (ks * 4 + (lane >> 4)) ^ (lane & 7);
        const int rA = w * 32 + (lane & 15);
        const int rB = lane & 15;
        short8 af[2], bfr[8];
#pragma unroll
        for (int mt = 0; mt < 2; ++mt)
          af[mt] = *(const short8*)&As[((rA + mt * 16) * 8 + swz) * 8];
#pragma unroll
        for (int nt = 0; nt < 8; ++nt)
          bfr[nt] = *(const short8*)&Bs[((rB + nt * 16) * 8 + swz) * 8];
#pragma unroll
        for (int mt = 0; mt < 2; ++mt)
#pragma unroll
          for (int nt = 0; nt < 8; ++nt)
            acc[mt][nt] = __builtin_amdgcn_mfma_f32_16x16x32_bf16(af[mt], bfr[nt], acc[mt][nt], 0, 0, 0);
      }
    }
  }

  const int col = lane & 15, rq = lane >> 4;
#pragma unroll
  for (int mt = 0; mt < 2; ++mt) {
#pragma unroll
    for (int nt = 0; nt < 4; ++nt) {
      int gcol = n0 + nt * 16 + col;
      float ba = bias[gcol];
      float bg = bias[512 + gcol];
#pragma unroll
      for (int r = 0; r < 4; ++r) {
        int grow = m0 + w * 32 + mt * 16 + rq * 4 + r;
        float a = acc[mt][nt][r] + ba;
        float gt = acc[mt][nt + 4][r] + bg;
        g[(size_t)grow * 512 + gcol] = a / (1.f + expf(-gt));
      }
    }
  }
}

// ---------------- depthwise conv + LN + swish + logit-dot + sigmoid ----------
// Writes alphas TRANSPOSED: aT[t*16 + b]
__global__ __launch_bounds__(512) void conv_ln_k(const float* __restrict__ g,
    const float* __restrict__ dw_w, const float* __restrict__ dw_b,
    const float* __restrict__ ln_g, const float* __restrict__ ln_b,
    const float* __restrict__ weff, const int* __restrict__ x_lens,
    float* __restrict__ aT) {
  __shared__ float wlds[H_ * K_];
  __shared__ float red1[16][8];
  __shared__ float red2[16][8];
  __shared__ float mvs[16], rss[16];
  const int tid = threadIdx.x;
  const int c = tid;
  const int t0 = blockIdx.x * 16;
  const int b = blockIdx.y;

  for (int i = tid; i < H_ * K_; i += 512) wlds[i] = dw_w[i];
  __syncthreads();

  const float* gb = g + ((size_t)b * T_) * H_ + c;
  float gv[30];
#pragma unroll
  for (int i = 0; i < 30; ++i) {
    int t = t0 - 14 + i;
    gv[i] = (t >= 0) ? gb[(size_t)t * H_] : 0.f;
  }
  float wreg[15];
#pragma unroll
  for (int k = 0; k < 15; ++k) wreg[k] = wlds[c * 15 + k];
  float dwb = dw_b[c];
  float h2[16];
#pragma unroll
  for (int j = 0; j < 16; ++j) {
    float s = dwb;
#pragma unroll
    for (int k = 0; k < 15; ++k) s += gv[j + k] * wreg[k];
    h2[j] = s;
  }
  const int lane = tid & 63, wid = tid >> 6;
#pragma unroll
  for (int j = 0; j < 16; ++j) {
    float s1 = h2[j], s2 = h2[j] * h2[j];
#pragma unroll
    for (int off = 32; off > 0; off >>= 1) {
      s1 += __shfl_down(s1, off, 64);
      s2 += __shfl_down(s2, off, 64);
    }
    if (lane == 0) { red1[j][wid] = s1; red2[j][wid] = s2; }
  }
  __syncthreads();
  if (tid < 16) {
    float s1 = 0.f, s2 = 0.f;
#pragma unroll
    for (int w = 0; w < 8; ++w) { s1 += red1[tid][w]; s2 += red2[tid][w]; }
    float m = s1 * (1.f / 512.f);
    float v = s2 * (1.f / 512.f) - m * m;
    mvs[tid] = m;
    rss[tid] = rsqrtf(v + 1e-5f);
  }
  __syncthreads();
  float lg = ln_g[c], lb = ln_b[c], we = weff[c];
#pragma unroll
  for (int j = 0; j < 16; ++j) {
    float y = (h2[j] - mvs[j]) * rss[j] * lg + lb;
    float sw = y / (1.f + expf(-y));
    float p = sw * we;
#pragma unroll
    for (int off = 32; off > 0; off >>= 1) p += __shfl_down(p, off, 64);
    if (lane == 0) red1[j][wid] = p;
  }
  __syncthreads();
  if (tid < 16) {
    float s = 0.f;
#pragma unroll
    for (int w = 0; w < 8; ++w) s += red1[tid][w];
    float logit = s + weff[H_];
    float a = 1.f / (1.f + expf(-logit));
    int t = t0 + tid;
    if (t >= x_lens[b]) a = 0.f;
    aT[t * B_ + b] = a;
  }
}

// ---------------- CIF phase 1: minimal integ recurrence + checkpoints --------
// chain per step: v_add -> v_floor -> v_sub (exact for ni in [0,2)).
// Stores integ at each 32-step segment start: chk[seg*B_+b], 64 segments.
__global__ __launch_bounds__(64) void cif_p1_k(const float* __restrict__ aT,
                                               float* __restrict__ chk) {
  const int b = threadIdx.x;
  if (b >= B_) return;
  const float* ar = aT + b;
  float integ = 0.f;
  float bufA[32], bufB[32];
#pragma unroll
  for (int j = 0; j < 32; ++j) bufA[j] = ar[j * B_];
#pragma unroll 1
  for (int s = 0; s < 64; s += 2) {
#pragma unroll
    for (int j = 0; j < 32; ++j) bufB[j] = ar[((s + 1) * 32 + j) * B_];
    chk[s * B_ + b] = integ;
#pragma unroll
    for (int j = 0; j < 32; ++j) {
      float ni = integ + bufA[j];
      integ = ni - floorf(ni);
    }
    if (s + 2 < 64) {
#pragma unroll
      for (int j = 0; j < 32; ++j) bufA[j] = ar[((s + 2) * 32 + j) * B_];
    }
    chk[(s + 1) * B_ + b] = integ;
#pragma unroll
    for (int j = 0; j < 32; ++j) {
      float ni = integ + bufB[j];
      integ = ni - floorf(ni);
    }
  }
}

// ---------------- CIF phase 2: parallel replay from checkpoints --------------
// Block = batch, lane = 32-step segment. Bit-identical replay of the chain
// reproduces phase-1 fire decisions exactly.
__global__ __launch_bounds__(64) void cif_p2_k(const float* __restrict__ aT,
    const float* __restrict__ chk, float* __restrict__ wdT, float* __restrict__ wrT,
    int* __restrict__ fire_pos, int* __restrict__ nfires, float* __restrict__ tok) {
  const int b = blockIdx.x;
  const int seg = threadIdx.x;
  const int t0 = seg * 32;
  float integ = chk[seg * B_ + b];
  float a[32];
#pragma unroll
  for (int j = 0; j < 32; ++j) a[j] = aT[(t0 + j) * B_ + b];
  unsigned fmask = 0u;
  float ssum = 0.f;
#pragma unroll
  for (int j = 0; j < 32; ++j) {
    float al = a[j];
    float dist = 1.0f - integ;
    float ni = integ + al;
    bool fire = ni >= 1.0f;
    float cur = fire ? dist : al;
    wdT[(t0 + j) * B_ + b] = cur;
    wrT[(t0 + j) * B_ + b] = al - cur;
    if (fire) fmask |= (1u << j);
    integ = ni - floorf(ni);
    ssum += al;
  }
  const int cnt = __popc(fmask);
  // inclusive prefix scan of cnt across the 64 lanes
  int incl = cnt;
#pragma unroll
  for (int off = 1; off < 64; off <<= 1) {
    int v = __shfl_up(incl, off, 64);
    if (seg >= off) incl += v;
  }
  int idx = incl - cnt;  // exclusive base
  unsigned m = fmask;
  while (m) {
    int j = __ffs(m) - 1;
    m &= m - 1;
    fire_pos[b * T_ + idx++] = t0 + j;
  }
  if (seg == 63) nfires[b] = incl;
#pragma unroll
  for (int off = 32; off > 0; off >>= 1) ssum += __shfl_down(ssum, off, 64);
  if (seg == 0) tok[b] = ssum;
}

// ---------------- gather fired frames + reversed copy + zero-fill tail -------
__global__ __launch_bounds__(128) void frames_k(const float* __restrict__ x,
    const float* __restrict__ aT, const float* __restrict__ wdT,
    const float* __restrict__ wrT, const int* __restrict__ fire_pos,
    const int* __restrict__ nfires, float* __restrict__ out0, float* __restrict__ out2) {
  const int b = blockIdx.y;
  const int j = blockIdx.x;
  const int h = threadIdx.x << 2;
  const size_t ob = ((size_t)b * T_ + j) * H_;
  if (j >= nfires[b]) {   // d_out is poisoned 0xAA: zero the unused rows here
    float4 z = make_float4(0.f, 0.f, 0.f, 0.f);
    *(float4*)(out0 + ob + h) = z;
    *(float4*)(out2 + ob + h) = z;
    return;
  }
  const int te = fire_pos[b * T_ + j];
  const int ts = (j > 0) ? fire_pos[b * T_ + j - 1] : -1;
  const float* xb = x + ((size_t)b * T_) * H_;
  float4 acc = make_float4(0.f, 0.f, 0.f, 0.f);
  if (j > 0) {
    float w = wrT[ts * B_ + b];
    float4 xv = *(const float4*)(xb + (size_t)ts * H_ + h);
    acc.x = w * xv.x; acc.y = w * xv.y; acc.z = w * xv.z; acc.w = w * xv.w;
  }
  for (int t = ts + 1; t < te; ++t) {
    float w = aT[t * B_ + b];
    float4 xv = *(const float4*)(xb + (size_t)t * H_ + h);
    acc.x += w * xv.x; acc.y += w * xv.y; acc.z += w * xv.z; acc.w += w * xv.w;
  }
  {
    float w = wdT[te * B_ + b];
    float4 xv = *(const float4*)(xb + (size_t)te * H_ + h);
    acc.x += w * xv.x; acc.y += w * xv.y; acc.z += w * xv.z; acc.w += w * xv.w;
  }
  *(float4*)(out0 + ob + h) = acc;
  float4 racc = make_float4(acc.w, acc.z, acc.y, acc.x);
  *(float4*)(out2 + ob + (H_ - 4 - h)) = racc;
}

extern "C" void kernel_launch(void* const* d_in, const int* in_sizes, int n_in,
                              void* d_out, int out_size, void* d_ws, size_t ws_size,
                              hipStream_t stream) {
  const float* x     = (const float*)d_in[0];
  const int*   xlens = (const int*)d_in[1];
  const float* pw1_w = (const float*)d_in[2];
  const float* pw1_b = (const float*)d_in[3];
  const float* dw_w  = (const float*)d_in[4];
  const float* dw_b  = (const float*)d_in[5];
  const float* ln_g  = (const float*)d_in[6];
  const float* ln_b  = (const float*)d_in[7];
  const float* pw2_w = (const float*)d_in[8];
  const float* pw2_b = (const float*)d_in[9];
  const float* lin_w = (const float*)d_in[10];
  const float* lin_b = (const float*)d_in[11];

  float* out0 = (float*)d_out;                       // fired_frames (B,T,H)
  float* tok  = out0 + (size_t)B_ * T_ * H_;         // predicted_token_nums (B,)
  float* out2 = tok + B_;                            // r_fired_frames (B,T,H)

  char* ws = (char*)d_ws;
  float* g             = (float*)ws;                              // 64 MB
  unsigned short* Ahi  = (unsigned short*)(ws + (size_t)M_ * H_ * 4);
  unsigned short* Alo  = Ahi + (size_t)M_ * H_;
  unsigned short* Whi  = Alo + (size_t)M_ * H_;
  unsigned short* Wlo  = Whi + (size_t)2 * H_ * H_;
  float* aT       = (float*)(Wlo + (size_t)2 * H_ * H_);
  float* wdT      = aT + B_ * T_;
  float* wrT      = wdT + B_ * T_;
  int*   fire_pos = (int*)(wrT + B_ * T_);
  int*   nfires   = fire_pos + B_ * T_;
  float* weff     = (float*)(nfires + 64);
  float* chk      = weff + 1024;   // 64 segments x 16 batches

  convx_k<<<2048, 256, 0, stream>>>(x, Ahi, Alo, M_ * H_ / 4);
  convx_k<<<256, 256, 0, stream>>>(pw1_w, Whi, Wlo, 2 * H_ * H_ / 4);
  weff_k<<<8, 256, 0, stream>>>(pw2_w, lin_w, weff);
  beff_k<<<1, 512, 0, stream>>>(pw2_b, lin_w, lin_b, weff);
  gemm_mfma_k<<<dim3(256, 8), 256, 0, stream>>>(Ahi, Alo, Whi, Wlo, pw1_b, g);
  conv_ln_k<<<dim3(128, 16), 512, 0, stream>>>(g, dw_w, dw_b, ln_g, ln_b, weff, xlens, aT);
  cif_p1_k<<<1, 64, 0, stream>>>(aT, chk);
  cif_p2_k<<<16, 64, 0, stream>>>(aT, chk, wdT, wrT, fire_pos, nfires, tok);
  frames_k<<<dim3(2048, 16), 128, 0, stream>>>(x, aT, wdT, wrT, fire_pos, nfires, out0, out2);
}

// Round 5
// 464.615 us; speedup vs baseline: 1.4212x; 1.0712x over previous
//
#include <hip/hip_runtime.h>
#include <math.h>

#define B_ 16
#define T_ 2048
#define H_ 512
#define K_ 15
#define M_ (B_*T_)   // 32768

typedef __attribute__((ext_vector_type(8))) short short8;
typedef __attribute__((ext_vector_type(4))) float f32x4;

__device__ __forceinline__ unsigned short f2bf(float f) {
  union { float f; unsigned u; } v; v.f = f;
  unsigned r = v.u + 0x7FFFu + ((v.u >> 16) & 1u);
  return (unsigned short)(r >> 16);
}
__device__ __forceinline__ float bf2f(unsigned short b) {
  union { float f; unsigned u; } v; v.u = ((unsigned)b) << 16;
  return v.f;
}

__device__ __forceinline__ void async_load16(const void* g, void* l) {
  __builtin_amdgcn_global_load_lds((const __attribute__((address_space(1))) void*)g,
                                   (__attribute__((address_space(3))) void*)l, 16, 0, 0);
}

// ---------------- fp32 -> (bf16 hi, bf16 lo) split conversion ----------------
__global__ void convx_k(const float* __restrict__ x, unsigned short* __restrict__ hi,
                        unsigned short* __restrict__ lo, int n4) {
  int i = blockIdx.x * blockDim.x + threadIdx.x;
  int stride = gridDim.x * blockDim.x;
  for (; i < n4; i += stride) {
    float4 v = ((const float4*)x)[i];
    ushort4 h, l;
    h.x = f2bf(v.x); l.x = f2bf(v.x - bf2f(h.x));
    h.y = f2bf(v.y); l.y = f2bf(v.y - bf2f(h.y));
    h.z = f2bf(v.z); l.z = f2bf(v.z - bf2f(h.z));
    h.w = f2bf(v.w); l.w = f2bf(v.w - bf2f(h.w));
    ((ushort4*)hi)[i] = h;
    ((ushort4*)lo)[i] = l;
  }
}

// ---------------- w_eff + b_eff (merged) -------------------------------------
__global__ __launch_bounds__(256) void weff_k(const float* __restrict__ pw2_w,
    const float* __restrict__ pw2_b, const float* __restrict__ lin_w,
    const float* __restrict__ lin_b, float* __restrict__ weff) {
  __shared__ float red[256];
  if (blockIdx.x < 8) {
    int h = blockIdx.x * 64 + (threadIdx.x & 63);
    int og = threadIdx.x >> 6;
    float acc = 0.f;
    for (int o = og * 128; o < og * 128 + 128; ++o) acc += pw2_w[o * H_ + h] * lin_w[o];
    red[threadIdx.x] = acc;
    __syncthreads();
    if (threadIdx.x < 64)
      weff[h] = red[threadIdx.x] + red[threadIdx.x + 64] + red[threadIdx.x + 128] + red[threadIdx.x + 192];
  } else {
    int i = threadIdx.x;
    red[i] = pw2_b[i] * lin_w[i] + pw2_b[i + 256] * lin_w[i + 256];
    __syncthreads();
    for (int s = 128; s > 0; s >>= 1) {
      if (i < s) red[i] += red[i + s];
      __syncthreads();
    }
    if (i == 0) weff[H_] = red[0] + lin_b[0];
  }
}

// ---------------- pw1 GEMM: single K-loop, 4-tile staging, 3 fused products --
// Block: 128 rows x 64 g-cols (C-cols: a=[n0,n0+64), gate=[n0+512,+64)).
// Waves 2x2: wave (wr,wc) = 64 rows x 32 g-cols. BK=32. LDS 4x8KB.
// Chunk swizzle: 16B chunk q of row r stored at slot q ^ ((r>>1)&3).
__global__ __launch_bounds__(256) void gemm_mfma_k(
    const unsigned short* __restrict__ Ahi, const unsigned short* __restrict__ Alo,
    const unsigned short* __restrict__ Whi, const unsigned short* __restrict__ Wlo,
    const float* __restrict__ bias, float* __restrict__ g) {
  __shared__ short Ah[128 * 32];
  __shared__ short Al[128 * 32];
  __shared__ short Bh[128 * 32];
  __shared__ short Bl[128 * 32];
  const int tid = threadIdx.x;
  const int m0 = blockIdx.x * 128;
  const int n0 = blockIdx.y * 64;
  const int w = tid >> 6, lane = tid & 63;
  const int wr = w >> 1, wc = w & 1;

  f32x4 acc[4][4];  // [mt][gate*2+ntp]
#pragma unroll
  for (int mt = 0; mt < 4; ++mt)
#pragma unroll
    for (int nt = 0; nt < 4; ++nt) acc[mt][nt] = (f32x4){0.f, 0.f, 0.f, 0.f};

  // staging geometry (element offsets into global, k-invariant)
  int offA[2], offB[2], ldsb[2];
#pragma unroll
  for (int j = 0; j < 2; ++j) {
    int L = j * 256 + tid;
    int r = L >> 2;
    int csrc = (L & 3) ^ ((r >> 1) & 3);
    offA[j] = (m0 + r) * 512 + csrc * 8;
    int wrow = (r < 64) ? (n0 + r) : (n0 + 448 + r);
    offB[j] = wrow * 512 + csrc * 8;
    ldsb[j] = __builtin_amdgcn_readfirstlane((j * 256 + w * 64) * 16);
  }

  // fragment byte addresses (k-invariant, single LDS buffer)
  const int q = lane >> 4;
  int aAddr[4], bAddr[4];
#pragma unroll
  for (int mt = 0; mt < 4; ++mt) {
    int rA = wr * 64 + mt * 16 + (lane & 15);
    aAddr[mt] = rA * 64 + (q ^ ((rA >> 1) & 3)) * 16;
  }
#pragma unroll
  for (int nt = 0; nt < 4; ++nt) {
    int rB = (nt >> 1) * 64 + wc * 32 + (nt & 1) * 16 + (lane & 15);
    bAddr[nt] = rB * 64 + (q ^ ((rB >> 1) & 3)) * 16;
  }

#pragma unroll 1
  for (int kk = 0; kk < 16; ++kk) {
    const int k0 = kk * 32;
    __syncthreads();
#pragma unroll
    for (int j = 0; j < 2; ++j) {
      async_load16(Ahi + offA[j] + k0, (char*)Ah + ldsb[j]);
      async_load16(Alo + offA[j] + k0, (char*)Al + ldsb[j]);
      async_load16(Whi + offB[j] + k0, (char*)Bh + ldsb[j]);
      async_load16(Wlo + offB[j] + k0, (char*)Bl + ldsb[j]);
    }
    __syncthreads();
    short8 ah[4], al[4], bh[4], bl[4];
#pragma unroll
    for (int mt = 0; mt < 4; ++mt) {
      ah[mt] = *(const short8*)((const char*)Ah + aAddr[mt]);
      al[mt] = *(const short8*)((const char*)Al + aAddr[mt]);
    }
#pragma unroll
    for (int nt = 0; nt < 4; ++nt) {
      bh[nt] = *(const short8*)((const char*)Bh + bAddr[nt]);
      bl[nt] = *(const short8*)((const char*)Bl + bAddr[nt]);
    }
#pragma unroll
    for (int mt = 0; mt < 4; ++mt)
#pragma unroll
      for (int nt = 0; nt < 4; ++nt) {
        acc[mt][nt] = __builtin_amdgcn_mfma_f32_16x16x32_bf16(ah[mt], bh[nt], acc[mt][nt], 0, 0, 0);
        acc[mt][nt] = __builtin_amdgcn_mfma_f32_16x16x32_bf16(al[mt], bh[nt], acc[mt][nt], 0, 0, 0);
        acc[mt][nt] = __builtin_amdgcn_mfma_f32_16x16x32_bf16(ah[mt], bl[nt], acc[mt][nt], 0, 0, 0);
      }
  }

  // epilogue: GLU (a and gate live in the SAME lane: acc[mt][ntp] / acc[mt][2+ntp])
  const int col = lane & 15, rq = lane >> 4;
#pragma unroll
  for (int mt = 0; mt < 4; ++mt) {
#pragma unroll
    for (int ntp = 0; ntp < 2; ++ntp) {
      int gcol = n0 + wc * 32 + ntp * 16 + col;
      float ba = bias[gcol];
      float bg = bias[512 + gcol];
#pragma unroll
      for (int r = 0; r < 4; ++r) {
        int m = m0 + wr * 64 + mt * 16 + rq * 4 + r;
        float a = acc[mt][ntp][r] + ba;
        float gt = acc[mt][2 + ntp][r] + bg;
        g[(size_t)m * 512 + gcol] = a / (1.f + expf(-gt));
      }
    }
  }
}

// ---------------- depthwise conv + LN + swish + logit-dot + sigmoid ----------
// 64 t per block, rolling register window, LDS-transpose reductions.
// Writes alphas TRANSPOSED: aT[t*16 + b]
__global__ __launch_bounds__(512) void conv_ln_k(const float* __restrict__ g,
    const float* __restrict__ dw_w, const float* __restrict__ dw_b,
    const float* __restrict__ ln_g, const float* __restrict__ ln_b,
    const float* __restrict__ weff, const int* __restrict__ x_lens,
    float* __restrict__ aT) {
  __shared__ float wlds[H_ * K_];     // 30 KB
  __shared__ float tbuf[16][512];     // 32 KB
  __shared__ float mvs[16], rss[16];
  const int tid = threadIdx.x;
  const int c = tid;
  const int t0 = blockIdx.x * 64;
  const int b = blockIdx.y;

  for (int i = tid; i < H_ * K_; i += 512) wlds[i] = dw_w[i];
  const int xlen = x_lens[b];
  const float* gb = g + ((size_t)b * T_) * H_ + c;

  float gwin[30];
#pragma unroll
  for (int i = 0; i < 30; ++i) {
    int t = t0 - 14 + i;
    gwin[i] = (t >= 0) ? gb[(size_t)t * H_] : 0.f;
  }
  __syncthreads();
  float wreg[15];
#pragma unroll
  for (int k = 0; k < 15; ++k) wreg[k] = wlds[c * 15 + k];
  const float dwb = dw_b[c], lg = ln_g[c], lb = ln_b[c], we = weff[c];
  const float beff = weff[H_];
  const int tt = tid >> 5, p = tid & 31;

#pragma unroll 1
  for (int qc = 0; qc < 4; ++qc) {
    float h2[16];
#pragma unroll
    for (int j = 0; j < 16; ++j) {
      float s = dwb;
#pragma unroll
      for (int k = 0; k < 15; ++k) s += gwin[j + k] * wreg[k];
      h2[j] = s;
      tbuf[j][c] = s;
    }
    __syncthreads();
    float s1 = 0.f, s2 = 0.f;
#pragma unroll
    for (int k = 0; k < 16; ++k) {
      float v = tbuf[tt][k * 32 + p];
      s1 += v; s2 += v * v;
    }
#pragma unroll
    for (int off = 16; off > 0; off >>= 1) {
      s1 += __shfl_down(s1, off, 32);
      s2 += __shfl_down(s2, off, 32);
    }
    if (p == 0) {
      float m = s1 * (1.f / 512.f);
      float v = s2 * (1.f / 512.f) - m * m;
      mvs[tt] = m;
      rss[tt] = rsqrtf(v + 1e-5f);
    }
    __syncthreads();
#pragma unroll
    for (int j = 0; j < 16; ++j) {
      float y = (h2[j] - mvs[j]) * rss[j] * lg + lb;
      float sw = y / (1.f + expf(-y));
      tbuf[j][c] = sw * we;
    }
    __syncthreads();
    float s = 0.f;
#pragma unroll
    for (int k = 0; k < 16; ++k) s += tbuf[tt][k * 32 + p];
#pragma unroll
    for (int off = 16; off > 0; off >>= 1) s += __shfl_down(s, off, 32);
    if (p == 0) {
      float logit = s + beff;
      float a = 1.f / (1.f + expf(-logit));
      int t = t0 + qc * 16 + tt;
      if (t >= xlen) a = 0.f;
      aT[t * B_ + b] = a;
    }
    if (qc < 3) {
#pragma unroll
      for (int i = 0; i < 14; ++i) gwin[i] = gwin[i + 16];
#pragma unroll
      for (int i = 0; i < 16; ++i)
        gwin[14 + i] = gb[(size_t)(t0 + qc * 16 + 16 + i) * H_];
    }
    __syncthreads();
  }
}

// ---------------- CIF phase 1: minimal integ recurrence + checkpoints --------
__global__ __launch_bounds__(64) void cif_p1_k(const float* __restrict__ aT,
                                               float* __restrict__ chk) {
  const int b = threadIdx.x;
  if (b >= B_) return;
  const float* ar = aT + b;
  float integ = 0.f;
  float bufA[32], bufB[32];
#pragma unroll
  for (int j = 0; j < 32; ++j) bufA[j] = ar[j * B_];
#pragma unroll 1
  for (int s = 0; s < 64; s += 2) {
#pragma unroll
    for (int j = 0; j < 32; ++j) bufB[j] = ar[((s + 1) * 32 + j) * B_];
    chk[s * B_ + b] = integ;
#pragma unroll
    for (int j = 0; j < 32; ++j) {
      float ni = integ + bufA[j];
      integ = ni - floorf(ni);
    }
    if (s + 2 < 64) {
#pragma unroll
      for (int j = 0; j < 32; ++j) bufA[j] = ar[((s + 2) * 32 + j) * B_];
    }
    chk[(s + 1) * B_ + b] = integ;
#pragma unroll
    for (int j = 0; j < 32; ++j) {
      float ni = integ + bufB[j];
      integ = ni - floorf(ni);
    }
  }
}

// ---------------- CIF phase 2: parallel replay from checkpoints --------------
__global__ __launch_bounds__(64) void cif_p2_k(const float* __restrict__ aT,
    const float* __restrict__ chk, float* __restrict__ wdT, float* __restrict__ wrT,
    int* __restrict__ fire_pos, int* __restrict__ nfires, float* __restrict__ tok) {
  const int b = blockIdx.x;
  const int seg = threadIdx.x;
  const int t0 = seg * 32;
  float integ = chk[seg * B_ + b];
  float a[32];
#pragma unroll
  for (int j = 0; j < 32; ++j) a[j] = aT[(t0 + j) * B_ + b];
  unsigned fmask = 0u;
  float ssum = 0.f;
#pragma unroll
  for (int j = 0; j < 32; ++j) {
    float al = a[j];
    float dist = 1.0f - integ;
    float ni = integ + al;
    bool fire = ni >= 1.0f;
    float cur = fire ? dist : al;
    wdT[(t0 + j) * B_ + b] = cur;
    wrT[(t0 + j) * B_ + b] = al - cur;
    if (fire) fmask |= (1u << j);
    integ = ni - floorf(ni);
    ssum += al;
  }
  const int cnt = __popc(fmask);
  int incl = cnt;
#pragma unroll
  for (int off = 1; off < 64; off <<= 1) {
    int v = __shfl_up(incl, off, 64);
    if (seg >= off) incl += v;
  }
  int idx = incl - cnt;
  unsigned m = fmask;
  while (m) {
    int j = __ffs(m) - 1;
    m &= m - 1;
    fire_pos[b * T_ + idx++] = t0 + j;
  }
  if (seg == 63) nfires[b] = incl;
#pragma unroll
  for (int off = 32; off > 0; off >>= 1) ssum += __shfl_down(ssum, off, 64);
  if (seg == 0) tok[b] = ssum;
}

// ---------------- gather fired frames + reversed copy + zero-fill tail -------
__global__ __launch_bounds__(128) void frames_k(const float* __restrict__ x,
    const float* __restrict__ aT, const float* __restrict__ wdT,
    const float* __restrict__ wrT, const int* __restrict__ fire_pos,
    const int* __restrict__ nfires, float* __restrict__ out0, float* __restrict__ out2) {
  const int b = blockIdx.y;
  const int j = blockIdx.x;
  const int h = threadIdx.x << 2;
  const size_t ob = ((size_t)b * T_ + j) * H_;
  if (j >= nfires[b]) {
    float4 z = make_float4(0.f, 0.f, 0.f, 0.f);
    *(float4*)(out0 + ob + h) = z;
    *(float4*)(out2 + ob + h) = z;
    return;
  }
  const int te = fire_pos[b * T_ + j];
  const int ts = (j > 0) ? fire_pos[b * T_ + j - 1] : -1;
  const float* xb = x + ((size_t)b * T_) * H_;
  float4 acc = make_float4(0.f, 0.f, 0.f, 0.f);
  if (j > 0) {
    float w = wrT[ts * B_ + b];
    float4 xv = *(const float4*)(xb + (size_t)ts * H_ + h);
    acc.x = w * xv.x; acc.y = w * xv.y; acc.z = w * xv.z; acc.w = w * xv.w;
  }
  for (int t = ts + 1; t < te; ++t) {
    float w = aT[t * B_ + b];
    float4 xv = *(const float4*)(xb + (size_t)t * H_ + h);
    acc.x += w * xv.x; acc.y += w * xv.y; acc.z += w * xv.z; acc.w += w * xv.w;
  }
  {
    float w = wdT[te * B_ + b];
    float4 xv = *(const float4*)(xb + (size_t)te * H_ + h);
    acc.x += w * xv.x; acc.y += w * xv.y; acc.z += w * xv.z; acc.w += w * xv.w;
  }
  *(float4*)(out0 + ob + h) = acc;
  float4 racc = make_float4(acc.w, acc.z, acc.y, acc.x);
  *(float4*)(out2 + ob + (H_ - 4 - h)) = racc;
}

extern "C" void kernel_launch(void* const* d_in, const int* in_sizes, int n_in,
                              void* d_out, int out_size, void* d_ws, size_t ws_size,
                              hipStream_t stream) {
  const float* x     = (const float*)d_in[0];
  const int*   xlens = (const int*)d_in[1];
  const float* pw1_w = (const float*)d_in[2];
  const float* pw1_b = (const float*)d_in[3];
  const float* dw_w  = (const float*)d_in[4];
  const float* dw_b  = (const float*)d_in[5];
  const float* ln_g  = (const float*)d_in[6];
  const float* ln_b  = (const float*)d_in[7];
  const float* pw2_w = (const float*)d_in[8];
  const float* pw2_b = (const float*)d_in[9];
  const float* lin_w = (const float*)d_in[10];
  const float* lin_b = (const float*)d_in[11];

  float* out0 = (float*)d_out;                       // fired_frames (B,T,H)
  float* tok  = out0 + (size_t)B_ * T_ * H_;         // predicted_token_nums (B,)
  float* out2 = tok + B_;                            // r_fired_frames (B,T,H)

  char* ws = (char*)d_ws;
  float* g             = (float*)ws;                              // 64 MB
  unsigned short* Ahi  = (unsigned short*)(ws + (size_t)M_ * H_ * 4);
  unsigned short* Alo  = Ahi + (size_t)M_ * H_;
  unsigned short* Whi  = Alo + (size_t)M_ * H_;
  unsigned short* Wlo  = Whi + (size_t)2 * H_ * H_;
  float* aT       = (float*)(Wlo + (size_t)2 * H_ * H_);
  float* wdT      = aT + B_ * T_;
  float* wrT      = wdT + B_ * T_;
  int*   fire_pos = (int*)(wrT + B_ * T_);
  int*   nfires   = fire_pos + B_ * T_;
  float* weff     = (float*)(nfires + 64);
  float* chk      = weff + 1024;   // 64 segments x 16 batches

  convx_k<<<2048, 256, 0, stream>>>(x, Ahi, Alo, M_ * H_ / 4);
  convx_k<<<256, 256, 0, stream>>>(pw1_w, Whi, Wlo, 2 * H_ * H_ / 4);
  weff_k<<<9, 256, 0, stream>>>(pw2_w, pw2_b, lin_w, lin_b, weff);
  gemm_mfma_k<<<dim3(256, 8), 256, 0, stream>>>(Ahi, Alo, Whi, Wlo, pw1_b, g);
  conv_ln_k<<<dim3(32, 16), 512, 0, stream>>>(g, dw_w, dw_b, ln_g, ln_b, weff, xlens, aT);
  cif_p1_k<<<1, 64, 0, stream>>>(aT, chk);
  cif_p2_k<<<16, 64, 0, stream>>>(aT, chk, wdT, wrT, fire_pos, nfires, tok);
  frames_k<<<dim3(2048, 16), 128, 0, stream>>>(x, aT, wdT, wrT, fire_pos, nfires, out0, out2);
}